// Round 1
// baseline (222.575 us; speedup 1.0000x reference)
//
#include <hip/hip_runtime.h>
#include <cstdint>

typedef unsigned short ushort_t;

#define M_ROWS 4096
#define N_COLS 3072
#define K_DIM  1024
#define S_LEN  2048
#define NHEADS 16
#define HDIM   64
#define QSCALE 0.1803368801111204f  /* (1/sqrt(64)) * log2(e) */

typedef __bf16 bf16_t;
typedef bf16_t  bf16x8  __attribute__((ext_vector_type(8)));
typedef short   shortx4 __attribute__((ext_vector_type(4)));
typedef float   floatx4 __attribute__((ext_vector_type(4)));
typedef ushort_t ushortx8 __attribute__((ext_vector_type(8)));

union U32x2S4 { unsigned u[2]; shortx4 s; };

__device__ __forceinline__ unsigned short f2bf(float f) {
  unsigned u = __float_as_uint(f);
  u += 0x7FFFu + ((u >> 16) & 1u);
  return (unsigned short)(u >> 16);
}

// pack two fp32 -> two bf16 (round-half-up) in one u32: low=a, high=b
__device__ __forceinline__ unsigned pkbf(float a, float b) {
  unsigned ua = __float_as_uint(a) + 0x8000u;
  unsigned ub = __float_as_uint(b) + 0x8000u;
  return __builtin_amdgcn_perm(ub, ua, 0x07060302u);
}

__device__ __forceinline__ float fexp2(float x) {
#if __has_builtin(__builtin_amdgcn_exp2f)
  return __builtin_amdgcn_exp2f(x);
#else
  float r; asm volatile("v_exp_f32 %0, %1\n\ts_nop 1" : "=v"(r) : "v"(x)); return r;
#endif
}

__device__ __forceinline__ void gload_lds16(const void* g, void* l) {
  __builtin_amdgcn_global_load_lds(
      (const __attribute__((address_space(1))) unsigned int*)g,
      (__attribute__((address_space(3))) unsigned int*)l,
      16, 0, 0);
}

/* ------------------------ fp32 -> bf16 convert ------------------------ */
__global__ __launch_bounds__(256) void cvt_bf16_kernel(
    const float* __restrict__ x, const float* __restrict__ w,
    ushort_t* __restrict__ Xb, ushort_t* __restrict__ Wb) {
  const int NX4 = (M_ROWS * K_DIM) / 4;
  int i = blockIdx.x * 256 + threadIdx.x;
  const float4* src;
  ushort_t* dst;
  int idx;
  if (i < NX4) { src = (const float4*)x; dst = Xb; idx = i; }
  else         { src = (const float4*)w; dst = Wb; idx = i - NX4; }
  float4 v = src[idx];
  ushort4 o;
  o.x = f2bf(v.x); o.y = f2bf(v.y); o.z = f2bf(v.z); o.w = f2bf(v.w);
  ((ushort4*)dst)[idx] = o;
}

/* ------------------------ QKV GEMM (m97 structure) ------------------------
   C[m,n] = sum_k X[m,k]*W[n,k] + b[n]; scatter bf16 into Q/K/V [b][h][s][64].
   Q gets the softmax scale folded in. */
__global__ __launch_bounds__(256) void qkv_gemm_kernel(
    const ushort_t* __restrict__ Xb, const ushort_t* __restrict__ Wb,
    const float* __restrict__ bias,
    ushort_t* __restrict__ Qb, ushort_t* __restrict__ Kb, ushort_t* __restrict__ Vb) {
  __shared__ ushort_t As[128 * 64];
  __shared__ ushort_t Bs[128 * 64];
  const int tid = threadIdx.x;
  const int l = tid & 63, w = tid >> 6;
  const int quad = l >> 4, lj = l & 15;
  const int m0 = blockIdx.y * 128, n0 = blockIdx.x * 128;
  const int wm = (w & 1) * 64, wn = (w >> 1) * 64;

  floatx4 acc[4][4] = {};

  const int srow = w * 32 + (l >> 3);
  const int scol = (l & 7) * 8;
  const ushort_t* gA = Xb + (size_t)(m0 + srow) * K_DIM + scol;
  const ushort_t* gB = Wb + (size_t)(n0 + srow) * K_DIM + scol;
  ushort_t* lA = As + (w * 32) * 64;
  ushort_t* lB = Bs + (w * 32) * 64;

  for (int k0 = 0; k0 < K_DIM; k0 += 64) {
    __syncthreads();
#pragma unroll
    for (int c = 0; c < 4; ++c) {
      gload_lds16(gA + (size_t)(c * 8) * K_DIM + k0, lA + c * 8 * 64);
      gload_lds16(gB + (size_t)(c * 8) * K_DIM + k0, lB + c * 8 * 64);
    }
    __syncthreads();
#pragma unroll
    for (int kk = 0; kk < 2; ++kk) {
      bf16x8 aF[4], bF[4];
#pragma unroll
      for (int i = 0; i < 4; ++i)
        aF[i] = *(const bf16x8*)(As + (wm + i * 16 + lj) * 64 + kk * 32 + quad * 8);
#pragma unroll
      for (int j = 0; j < 4; ++j)
        bF[j] = *(const bf16x8*)(Bs + (wn + j * 16 + lj) * 64 + kk * 32 + quad * 8);
#pragma unroll
      for (int i = 0; i < 4; ++i)
#pragma unroll
        for (int j = 0; j < 4; ++j)
          acc[i][j] = __builtin_amdgcn_mfma_f32_16x16x32_bf16(aF[i], bF[j], acc[i][j], 0, 0, 0);
    }
  }

  /* epilogue: n = h*192 + r; r<64 -> Q, r<128 -> K, else V */
#pragma unroll
  for (int j = 0; j < 4; ++j) {
    const int n = n0 + wn + j * 16 + lj;
    const int h = n / 192;
    const int r = n - h * 192;
    const int seg = r >> 6;
    const int d = r & 63;
    const float bv = bias[n];
    ushort_t* dst = (seg == 0) ? Qb : (seg == 1) ? Kb : Vb;
    const float scl = (seg == 0) ? QSCALE : 1.0f;
    const size_t base = (size_t)h * S_LEN * HDIM + d;
#pragma unroll
    for (int i = 0; i < 4; ++i) {
#pragma unroll
      for (int rg = 0; rg < 4; ++rg) {
        const int m = m0 + wm + i * 16 + quad * 4 + rg;
        const int bi = m >> 11;
        const int si = m & 2047;
        dst[base + ((size_t)bi * NHEADS * S_LEN + si) * HDIM] =
            f2bf((acc[i][j][rg] + bv) * scl);
      }
    }
  }
}

/* ------------------------ flash attention ------------------------
   Per block: one (b,h), 128 q-rows. Wave handles 32 q-rows.
   S^T = K*Q^T via mfma 16x16x32 (C-layout: col=lane&15 -> q, row=quad*4+reg -> key).
   P^T C-layout registers == A-operand layout of mfma 16x16x16bf16_1k (k=quad*4+j)
   -> PV with zero-cost transform. V staged transposed [d][s] in LDS. */
__global__ __launch_bounds__(256) void attn_kernel(
    const ushort_t* __restrict__ Qb, const ushort_t* __restrict__ Kb,
    const ushort_t* __restrict__ Vb, float* __restrict__ out) {
  __shared__ ushort_t Ks[128 * 64];
  __shared__ ushort_t Vs[64 * 140];
  const int tid = threadIdx.x;
  const int l = tid & 63, w = tid >> 6;
  const int quad = l >> 4, lj = l & 15;
  const int bh = blockIdx.x >> 4;
  const int qt = blockIdx.x & 15;
  const int q0 = qt * 128 + w * 32;
  const size_t headoff = (size_t)bh * S_LEN * HDIM;

  bf16x8 qF[2][2];
#pragma unroll
  for (int rt = 0; rt < 2; ++rt)
#pragma unroll
    for (int kk = 0; kk < 2; ++kk)
      qF[rt][kk] = *(const bf16x8*)(Qb + headoff + (size_t)(q0 + rt * 16 + lj) * HDIM +
                                    kk * 32 + quad * 8);

  floatx4 accO[2][4] = {};
  float m_run[2] = {-__builtin_inff(), -__builtin_inff()};
  float l_run[2] = {0.f, 0.f};

  const ushort_t* gK = Kb + headoff + (size_t)(w * 32 + (l >> 3)) * HDIM + (l & 7) * 8;
  ushort_t* lK = Ks + (w * 32) * 64;
  const int vd0 = (tid & 7) * 8;
  const int vs = tid >> 3; /* 0..31 */
  const ushort_t* gV = Vb + headoff + (size_t)vs * HDIM + vd0;

  for (int kb = 0; kb < 16; ++kb) {
    const int kv0 = kb * 128;
    __syncthreads();
    /* stage K [128][64] straight copy */
#pragma unroll
    for (int c = 0; c < 4; ++c)
      gload_lds16(gK + (size_t)(kv0 + c * 8) * HDIM, lK + c * 8 * 64);
    /* stage V transposed into Vs[d][s], stride 140 */
#pragma unroll
    for (int R = 0; R < 4; ++R) {
      ushortx8 vv = *(const ushortx8*)(gV + (size_t)(kv0 + R * 32) * HDIM);
      const int sc = R * 32 + vs;
#pragma unroll
      for (int e = 0; e < 8; ++e)
        Vs[(vd0 + e) * 140 + sc] = vv[e];
    }
    __syncthreads();

    /* S^T = K * Q^T  (accST[c][rt]: key-tile c, q-tile rt) */
    floatx4 accST[8][2];
#pragma unroll
    for (int c = 0; c < 8; ++c) {
      const ushort_t* kp = Ks + (c * 16 + lj) * 64 + quad * 8;
      bf16x8 kF0 = *(const bf16x8*)(kp);
      bf16x8 kF1 = *(const bf16x8*)(kp + 32);
#pragma unroll
      for (int rt = 0; rt < 2; ++rt) {
        floatx4 z = {0.f, 0.f, 0.f, 0.f};
        z = __builtin_amdgcn_mfma_f32_16x16x32_bf16(kF0, qF[rt][0], z, 0, 0, 0);
        accST[c][rt] = __builtin_amdgcn_mfma_f32_16x16x32_bf16(kF1, qF[rt][1], z, 0, 0, 0);
      }
    }

    /* online softmax; scores already scaled by log2(e)/8 via Q */
    shortx4 aP[2][8];
    float alpha[2];
#pragma unroll
    for (int rt = 0; rt < 2; ++rt) {
      float mx = accST[0][rt][0];
#pragma unroll
      for (int c = 0; c < 8; ++c)
#pragma unroll
        for (int rg = 0; rg < 4; ++rg)
          mx = fmaxf(mx, accST[c][rt][rg]);
      mx = fmaxf(mx, __shfl_xor(mx, 16, 64));
      mx = fmaxf(mx, __shfl_xor(mx, 32, 64));
      const float mnew = fmaxf(m_run[rt], mx);
      const float a = fexp2(m_run[rt] - mnew);
      m_run[rt] = mnew;
      alpha[rt] = a;
      float lsum = 0.f;
#pragma unroll
      for (int c = 0; c < 8; ++c) {
        float p0 = fexp2(accST[c][rt][0] - mnew);
        float p1 = fexp2(accST[c][rt][1] - mnew);
        float p2 = fexp2(accST[c][rt][2] - mnew);
        float p3 = fexp2(accST[c][rt][3] - mnew);
        lsum += (p0 + p1) + (p2 + p3);
        U32x2S4 t;
        t.u[0] = pkbf(p0, p1);
        t.u[1] = pkbf(p2, p3);
        aP[rt][c] = t.s;
      }
      l_run[rt] = l_run[rt] * a + lsum;
    }

    /* rescale O: alpha indexed by the accumulator's q-row (quad*4+rg) */
#pragma unroll
    for (int rt = 0; rt < 2; ++rt) {
      const int sbase = (l & 48) | (quad * 4);
      float a0 = __shfl(alpha[rt], sbase + 0, 64);
      float a1 = __shfl(alpha[rt], sbase + 1, 64);
      float a2 = __shfl(alpha[rt], sbase + 2, 64);
      float a3 = __shfl(alpha[rt], sbase + 3, 64);
#pragma unroll
      for (int dt = 0; dt < 4; ++dt) {
        accO[rt][dt][0] *= a0;
        accO[rt][dt][1] *= a1;
        accO[rt][dt][2] *= a2;
        accO[rt][dt][3] *= a3;
      }
    }

    /* O += P * V  via 16x16x16 bf16 (A = P from registers, B = V from Vs) */
#pragma unroll
    for (int dt = 0; dt < 4; ++dt) {
      const ushort_t* vp = Vs + (dt * 16 + lj) * 140 + quad * 4;
#pragma unroll
      for (int c = 0; c < 8; ++c) {
        shortx4 vF = *(const shortx4*)(vp + c * 16);
        accO[0][dt] = __builtin_amdgcn_mfma_f32_16x16x16bf16_1k(aP[0][c], vF, accO[0][dt], 0, 0, 0);
        accO[1][dt] = __builtin_amdgcn_mfma_f32_16x16x16bf16_1k(aP[1][c], vF, accO[1][dt], 0, 0, 0);
      }
    }
  }

  /* epilogue: O /= l, store fp32 in [b][h][s][d] flat (== reference reshape) */
#pragma unroll
  for (int rt = 0; rt < 2; ++rt) {
    float ls = l_run[rt];
    ls += __shfl_xor(ls, 16, 64);
    ls += __shfl_xor(ls, 32, 64);
    const float inv = 1.0f / ls;
    const int sbase = (l & 48) | (quad * 4);
    float iv[4];
    iv[0] = __shfl(inv, sbase + 0, 64);
    iv[1] = __shfl(inv, sbase + 1, 64);
    iv[2] = __shfl(inv, sbase + 2, 64);
    iv[3] = __shfl(inv, sbase + 3, 64);
#pragma unroll
    for (int dt = 0; dt < 4; ++dt) {
#pragma unroll
      for (int rg = 0; rg < 4; ++rg) {
        const int q = q0 + rt * 16 + quad * 4 + rg;
        out[headoff + (size_t)q * HDIM + dt * 16 + lj] = accO[rt][dt][rg] * iv[rg];
      }
    }
  }
}

extern "C" void kernel_launch(void* const* d_in, const int* in_sizes, int n_in,
                              void* d_out, int out_size, void* d_ws, size_t ws_size,
                              hipStream_t stream) {
  (void)in_sizes; (void)n_in; (void)out_size; (void)ws_size;
  const float* x  = (const float*)d_in[0];
  const float* wq = (const float*)d_in[1];
  const float* bq = (const float*)d_in[2];
  float* out = (float*)d_out;

  char* ws = (char*)d_ws;
  /* workspace map (bytes):
     Qb 0..8388608, Kb ..16777216, Vb ..25165824  (each [2][16][2048][64] bf16)
     Xb ..33554432 (4096x1024 bf16), Wb ..39845888 (3072x1024 bf16) */
  ushort_t* Qb = (ushort_t*)(ws);
  ushort_t* Kb = (ushort_t*)(ws + 8388608);
  ushort_t* Vb = (ushort_t*)(ws + 16777216);
  ushort_t* Xb = (ushort_t*)(ws + 25165824);
  ushort_t* Wb = (ushort_t*)(ws + 33554432);

  cvt_bf16_kernel<<<7168, 256, 0, stream>>>(x, wq, Xb, Wb);
  qkv_gemm_kernel<<<dim3(N_COLS / 128, M_ROWS / 128), 256, 0, stream>>>(Xb, Wb, bq, Qb, Kb, Vb);
  attn_kernel<<<512, 256, 0, stream>>>(Qb, Kb, Vb, out);
}

// Round 2
// 195.407 us; speedup vs baseline: 1.1390x; 1.1390x over previous
//
#include <hip/hip_runtime.h>
#include <cstdint>

typedef unsigned short ushort_t;

#define M_ROWS 4096
#define N_COLS 3072
#define K_DIM  1024
#define S_LEN  2048
#define NHEADS 16
#define HDIM   64
#define QSCALE 0.1803368801111204f  /* (1/sqrt(64)) * log2(e) */

typedef __bf16 bf16_t;
typedef bf16_t  bf16x8  __attribute__((ext_vector_type(8)));
typedef short   shortx4 __attribute__((ext_vector_type(4)));
typedef float   floatx4 __attribute__((ext_vector_type(4)));
typedef ushort_t ushortx4 __attribute__((ext_vector_type(4)));
typedef ushort_t ushortx8 __attribute__((ext_vector_type(8)));

union U32x2S4 { unsigned u[2]; shortx4 s; };
union U32S2   { unsigned u; ushortx4 v2[0]; };

__device__ __forceinline__ unsigned short f2bf(float f) {
  unsigned u = __float_as_uint(f);
  u += 0x7FFFu + ((u >> 16) & 1u);
  return (unsigned short)(u >> 16);
}

// pack two fp32 -> two bf16 (round-half-up) in one u32: low=a, high=b
__device__ __forceinline__ unsigned pkbf(float a, float b) {
  unsigned ua = __float_as_uint(a) + 0x8000u;
  unsigned ub = __float_as_uint(b) + 0x8000u;
  return __builtin_amdgcn_perm(ub, ua, 0x07060302u);
}

__device__ __forceinline__ float fexp2(float x) {
#if __has_builtin(__builtin_amdgcn_exp2f)
  return __builtin_amdgcn_exp2f(x);
#else
  float r; asm volatile("v_exp_f32 %0, %1\n\ts_nop 1" : "=v"(r) : "v"(x)); return r;
#endif
}

__device__ __forceinline__ void gload_lds16(const void* g, void* l) {
  __builtin_amdgcn_global_load_lds(
      (const __attribute__((address_space(1))) unsigned int*)g,
      (__attribute__((address_space(3))) unsigned int*)l,
      16, 0, 0);
}

/* ------------------------ fp32 -> bf16 convert ------------------------ */
__global__ __launch_bounds__(256) void cvt_bf16_kernel(
    const float* __restrict__ x, const float* __restrict__ w,
    ushort_t* __restrict__ Xb, ushort_t* __restrict__ Wb) {
  const int NX4 = (M_ROWS * K_DIM) / 4;
  int i = blockIdx.x * 256 + threadIdx.x;
  const float4* src;
  ushort_t* dst;
  int idx;
  if (i < NX4) { src = (const float4*)x; dst = Xb; idx = i; }
  else         { src = (const float4*)w; dst = Wb; idx = i - NX4; }
  float4 v = src[idx];
  ushort4 o;
  o.x = f2bf(v.x); o.y = f2bf(v.y); o.z = f2bf(v.z); o.w = f2bf(v.w);
  ((ushort4*)dst)[idx] = o;
}

/* ------------------------ QKV GEMM (m97 structure, unchanged) ------------ */
__global__ __launch_bounds__(256) void qkv_gemm_kernel(
    const ushort_t* __restrict__ Xb, const ushort_t* __restrict__ Wb,
    const float* __restrict__ bias,
    ushort_t* __restrict__ Qb, ushort_t* __restrict__ Kb, ushort_t* __restrict__ Vb) {
  __shared__ ushort_t As[128 * 64];
  __shared__ ushort_t Bs[128 * 64];
  const int tid = threadIdx.x;
  const int l = tid & 63, w = tid >> 6;
  const int quad = l >> 4, lj = l & 15;
  const int m0 = blockIdx.y * 128, n0 = blockIdx.x * 128;
  const int wm = (w & 1) * 64, wn = (w >> 1) * 64;

  floatx4 acc[4][4] = {};

  const int srow = w * 32 + (l >> 3);
  const int scol = (l & 7) * 8;
  const ushort_t* gA = Xb + (size_t)(m0 + srow) * K_DIM + scol;
  const ushort_t* gB = Wb + (size_t)(n0 + srow) * K_DIM + scol;
  ushort_t* lA = As + (w * 32) * 64;
  ushort_t* lB = Bs + (w * 32) * 64;

  for (int k0 = 0; k0 < K_DIM; k0 += 64) {
    __syncthreads();
#pragma unroll
    for (int c = 0; c < 4; ++c) {
      gload_lds16(gA + (size_t)(c * 8) * K_DIM + k0, lA + c * 8 * 64);
      gload_lds16(gB + (size_t)(c * 8) * K_DIM + k0, lB + c * 8 * 64);
    }
    __syncthreads();
#pragma unroll
    for (int kk = 0; kk < 2; ++kk) {
      bf16x8 aF[4], bF[4];
#pragma unroll
      for (int i = 0; i < 4; ++i)
        aF[i] = *(const bf16x8*)(As + (wm + i * 16 + lj) * 64 + kk * 32 + quad * 8);
#pragma unroll
      for (int j = 0; j < 4; ++j)
        bF[j] = *(const bf16x8*)(Bs + (wn + j * 16 + lj) * 64 + kk * 32 + quad * 8);
#pragma unroll
      for (int i = 0; i < 4; ++i)
#pragma unroll
        for (int j = 0; j < 4; ++j)
          acc[i][j] = __builtin_amdgcn_mfma_f32_16x16x32_bf16(aF[i], bF[j], acc[i][j], 0, 0, 0);
    }
  }

  /* epilogue: n = h*192 + r; r<64 -> Q, r<128 -> K, else V */
#pragma unroll
  for (int j = 0; j < 4; ++j) {
    const int n = n0 + wn + j * 16 + lj;
    const int h = n / 192;
    const int r = n - h * 192;
    const int seg = r >> 6;
    const int d = r & 63;
    const float bv = bias[n];
    ushort_t* dst = (seg == 0) ? Qb : (seg == 1) ? Kb : Vb;
    const float scl = (seg == 0) ? QSCALE : 1.0f;
    const size_t base = (size_t)h * S_LEN * HDIM + d;
#pragma unroll
    for (int i = 0; i < 4; ++i) {
#pragma unroll
      for (int rg = 0; rg < 4; ++rg) {
        const int m = m0 + wm + i * 16 + quad * 4 + rg;
        const int bi = m >> 11;
        const int si = m & 2047;
        dst[base + ((size_t)bi * NHEADS * S_LEN + si) * HDIM] =
            f2bf((acc[i][j][rg] + bv) * scl);
      }
    }
  }
}

/* ------------------------ flash attention (v2) ------------------------
   Block: 512 threads = 8 waves, one (b,h), 128 q-rows; wave handles 16 q-rows.
   S^T = K*Q^T via mfma 16x16x32 (C: col=lane&15=q, row=quad*4+reg=key).
   P^T C-layout regs == A-operand of mfma 16x16x16bf16_1k -> free PV transform.
   V staged transposed [d][s] stride 140 with XOR swizzle
   s' = s ^ (((d>>4)&3)<<2)  -> 2-way (free) LDS write banks; read side is
   just quad^dt. Staging: coalesced b64 global loads + v_perm pack + b32 LDS
   writes (replaces round-1's 32 conflicted scalar u16 scatter writes). */
__global__ __launch_bounds__(512, 4) void attn_kernel(
    const ushort_t* __restrict__ Qb, const ushort_t* __restrict__ Kb,
    const ushort_t* __restrict__ Vb, float* __restrict__ out) {
  __shared__ ushort_t Ks[128 * 64];
  __shared__ ushort_t Vs[64 * 140];
  const int tid = threadIdx.x;
  const int l = tid & 63, w = tid >> 6;
  const int quad = l >> 4, lj = l & 15;
  const int bh = blockIdx.x >> 4;
  const int qt = blockIdx.x & 15;
  const int q0 = qt * 128 + w * 16;
  const size_t headoff = (size_t)bh * S_LEN * HDIM;

  /* Q fragments: B-operand, n=q=lj, k = kk*32 + quad*8 + j */
  bf16x8 qF[2];
#pragma unroll
  for (int kk = 0; kk < 2; ++kk)
    qF[kk] = *(const bf16x8*)(Qb + headoff + (size_t)(q0 + lj) * HDIM +
                              kk * 32 + quad * 8);

  floatx4 accO[4] = {};
  float m_run = -__builtin_inff();
  float l_run = 0.f;

  /* K staging: thread t covers row t>>3 (+64c), cols (t&7)*8.. ; LDS dest is
     lane-contiguous: Ks + tid*8 ushorts == wavebase + lane*16B. */
  const ushort_t* gK = Kb + headoff + (size_t)(tid >> 3) * HDIM + (tid & 7) * 8;
  ushort_t* lK = Ks + tid * 8;

  /* V staging: thread covers (s pair 2sp..2sp+1) x (d quad 4dq..4dq+3), R=0,1 */
  const int dq = tid & 15;
  const int spw = tid >> 4; /* 0..31 */
  const ushort_t* gV = Vb + headoff + dq * 4;
  unsigned* Vs32 = (unsigned*)Vs;
  const int swz = (dq >> 2) << 1; /* swizzle in u32-column units */

  for (int kb = 0; kb < 16; ++kb) {
    const int kv0 = kb * 128;
    __syncthreads();
#pragma unroll
    for (int c = 0; c < 2; ++c)
      gload_lds16(gK + (size_t)(kv0 + c * 64) * HDIM, lK + c * 64 * 64);
#pragma unroll
    for (int R = 0; R < 2; ++R) {
      const int sp = R * 32 + spw; /* 0..63 */
      const ushort_t* g = gV + (size_t)(kv0 + 2 * sp) * HDIM;
      U32S2 A0, A1, B0, B1;
      ushortx4 v0 = *(const ushortx4*)g;
      ushortx4 v1 = *(const ushortx4*)(g + HDIM);
      unsigned a0 = ((unsigned)(ushort_t)v0[1] << 16) | (ushort_t)v0[0];
      unsigned a1 = ((unsigned)(ushort_t)v0[3] << 16) | (ushort_t)v0[2];
      unsigned b0 = ((unsigned)(ushort_t)v1[1] << 16) | (ushort_t)v1[0];
      unsigned b1 = ((unsigned)(ushort_t)v1[3] << 16) | (ushort_t)v1[2];
      unsigned o0 = __builtin_amdgcn_perm(b0, a0, 0x05040100u);
      unsigned o1 = __builtin_amdgcn_perm(b0, a0, 0x07060302u);
      unsigned o2 = __builtin_amdgcn_perm(b1, a1, 0x05040100u);
      unsigned o3 = __builtin_amdgcn_perm(b1, a1, 0x07060302u);
      const int sp2 = sp ^ swz;
      Vs32[(4 * dq + 0) * 70 + sp2] = o0;
      Vs32[(4 * dq + 1) * 70 + sp2] = o1;
      Vs32[(4 * dq + 2) * 70 + sp2] = o2;
      Vs32[(4 * dq + 3) * 70 + sp2] = o3;
    }
    __syncthreads();

    /* S^T = K * Q^T : accST[c], key = c*16 + quad*4 + rg, q = lj */
    floatx4 accST[8];
#pragma unroll
    for (int c = 0; c < 8; ++c) {
      const ushort_t* kp = Ks + (c * 16 + lj) * 64 + quad * 8;
      bf16x8 kF0 = *(const bf16x8*)(kp);
      bf16x8 kF1 = *(const bf16x8*)(kp + 32);
      floatx4 z = {0.f, 0.f, 0.f, 0.f};
      z = __builtin_amdgcn_mfma_f32_16x16x32_bf16(kF0, qF[0], z, 0, 0, 0);
      accST[c] = __builtin_amdgcn_mfma_f32_16x16x32_bf16(kF1, qF[1], z, 0, 0, 0);
    }

    /* online softmax (scores pre-scaled by log2(e)/8 via Q) */
    float mx = accST[0][0];
#pragma unroll
    for (int c = 0; c < 8; ++c)
#pragma unroll
      for (int rg = 0; rg < 4; ++rg)
        mx = fmaxf(mx, accST[c][rg]);
    mx = fmaxf(mx, __shfl_xor(mx, 16, 64));
    mx = fmaxf(mx, __shfl_xor(mx, 32, 64));
    const float mnew = fmaxf(m_run, mx);
    const float alpha = fexp2(m_run - mnew);
    m_run = mnew;
    shortx4 aP[8];
    float lsum = 0.f;
#pragma unroll
    for (int c = 0; c < 8; ++c) {
      float p0 = fexp2(accST[c][0] - mnew);
      float p1 = fexp2(accST[c][1] - mnew);
      float p2 = fexp2(accST[c][2] - mnew);
      float p3 = fexp2(accST[c][3] - mnew);
      lsum += (p0 + p1) + (p2 + p3);
      U32x2S4 t;
      t.u[0] = pkbf(p0, p1);
      t.u[1] = pkbf(p2, p3);
      aP[c] = t.s;
    }
    l_run = l_run * alpha + lsum;

    /* rescale O: alpha per accumulator q-row (quad*4+rg); alpha is uniform
       across quads for a given lj after the shfl reduction */
    {
      const int sbase = (l & 48) | (quad * 4);
      float a0 = __shfl(alpha, sbase + 0, 64);
      float a1 = __shfl(alpha, sbase + 1, 64);
      float a2 = __shfl(alpha, sbase + 2, 64);
      float a3 = __shfl(alpha, sbase + 3, 64);
#pragma unroll
      for (int dt = 0; dt < 4; ++dt) {
        accO[dt][0] *= a0;
        accO[dt][1] *= a1;
        accO[dt][2] *= a2;
        accO[dt][3] *= a3;
      }
    }

    /* O += P * V via 16x16x16 bf16; B-frag read applies swizzle via quad^dt */
#pragma unroll
    for (int dt = 0; dt < 4; ++dt) {
      const ushort_t* vp = Vs + (dt * 16 + lj) * 140 + (quad ^ dt) * 4;
#pragma unroll
      for (int c = 0; c < 8; ++c) {
        shortx4 vF = *(const shortx4*)(vp + c * 16);
        accO[dt] = __builtin_amdgcn_mfma_f32_16x16x16bf16_1k(aP[c], vF, accO[dt], 0, 0, 0);
      }
    }
  }

  /* epilogue: O /= l, store fp32 in [b][h][s][d] flat */
  {
    float ls = l_run;
    ls += __shfl_xor(ls, 16, 64);
    ls += __shfl_xor(ls, 32, 64);
    const float inv = 1.0f / ls;
    const int sbase = (l & 48) | (quad * 4);
    float iv[4];
    iv[0] = __shfl(inv, sbase + 0, 64);
    iv[1] = __shfl(inv, sbase + 1, 64);
    iv[2] = __shfl(inv, sbase + 2, 64);
    iv[3] = __shfl(inv, sbase + 3, 64);
#pragma unroll
    for (int dt = 0; dt < 4; ++dt) {
#pragma unroll
      for (int rg = 0; rg < 4; ++rg) {
        const int q = q0 + quad * 4 + rg;
        out[headoff + (size_t)q * HDIM + dt * 16 + lj] = accO[dt][rg] * iv[rg];
      }
    }
  }
}

extern "C" void kernel_launch(void* const* d_in, const int* in_sizes, int n_in,
                              void* d_out, int out_size, void* d_ws, size_t ws_size,
                              hipStream_t stream) {
  (void)in_sizes; (void)n_in; (void)out_size; (void)ws_size;
  const float* x  = (const float*)d_in[0];
  const float* wq = (const float*)d_in[1];
  const float* bq = (const float*)d_in[2];
  float* out = (float*)d_out;

  char* ws = (char*)d_ws;
  ushort_t* Qb = (ushort_t*)(ws);
  ushort_t* Kb = (ushort_t*)(ws + 8388608);
  ushort_t* Vb = (ushort_t*)(ws + 16777216);
  ushort_t* Xb = (ushort_t*)(ws + 25165824);
  ushort_t* Wb = (ushort_t*)(ws + 33554432);

  cvt_bf16_kernel<<<7168, 256, 0, stream>>>(x, wq, Xb, Wb);
  qkv_gemm_kernel<<<dim3(N_COLS / 128, M_ROWS / 128), 256, 0, stream>>>(Xb, Wb, bq, Qb, Kb, Vb);
  attn_kernel<<<512, 512, 0, stream>>>(Qb, Kb, Vb, out);
}

// Round 3
// 168.803 us; speedup vs baseline: 1.3186x; 1.1576x over previous
//
#include <hip/hip_runtime.h>
#include <cstdint>

typedef unsigned short ushort_t;

#define M_ROWS 4096
#define N_COLS 3072
#define K_DIM  1024
#define S_LEN  2048
#define NHEADS 16
#define HDIM   64
#define QSCALE 0.1803368801111204f  /* (1/sqrt(64)) * log2(e) */

typedef __bf16 bf16_t;
typedef bf16_t  bf16x8  __attribute__((ext_vector_type(8)));
typedef short   shortx4 __attribute__((ext_vector_type(4)));
typedef float   floatx4 __attribute__((ext_vector_type(4)));
typedef ushort_t ushortx4 __attribute__((ext_vector_type(4)));

union U32x2S4 { unsigned u[2]; shortx4 s; };

__device__ __forceinline__ unsigned short f2bf(float f) {
  unsigned u = __float_as_uint(f);
  u += 0x7FFFu + ((u >> 16) & 1u);
  return (unsigned short)(u >> 16);
}

// pack two fp32 -> two bf16 (round-half-up) in one u32: low=a, high=b
__device__ __forceinline__ unsigned pkbf(float a, float b) {
  unsigned ua = __float_as_uint(a) + 0x8000u;
  unsigned ub = __float_as_uint(b) + 0x8000u;
  return __builtin_amdgcn_perm(ub, ua, 0x07060302u);
}

__device__ __forceinline__ float fexp2(float x) {
#if __has_builtin(__builtin_amdgcn_exp2f)
  return __builtin_amdgcn_exp2f(x);
#else
  float r; asm volatile("v_exp_f32 %0, %1\n\ts_nop 1" : "=v"(r) : "v"(x)); return r;
#endif
}

__device__ __forceinline__ void gload_lds16(const void* g, void* l) {
  __builtin_amdgcn_global_load_lds(
      (const __attribute__((address_space(1))) unsigned int*)g,
      (__attribute__((address_space(3))) unsigned int*)l,
      16, 0, 0);
}

/* ------------------------ fp32 -> bf16 convert ------------------------ */
__global__ __launch_bounds__(256) void cvt_bf16_kernel(
    const float* __restrict__ x, const float* __restrict__ w,
    ushort_t* __restrict__ Xb, ushort_t* __restrict__ Wb) {
  const int NX4 = (M_ROWS * K_DIM) / 4;
  int i = blockIdx.x * 256 + threadIdx.x;
  const float4* src;
  ushort_t* dst;
  int idx;
  if (i < NX4) { src = (const float4*)x; dst = Xb; idx = i; }
  else         { src = (const float4*)w; dst = Wb; idx = i - NX4; }
  float4 v = src[idx];
  ushort4 o;
  o.x = f2bf(v.x); o.y = f2bf(v.y); o.z = f2bf(v.z); o.w = f2bf(v.w);
  ((ushort4*)dst)[idx] = o;
}

/* ------------------------ QKV GEMM (m97 structure + LDS XOR swizzle) ------
   LDS rows are 128 B (all rows bank-aligned) -> un-swizzled fragment reads
   are ~16-way bank conflicted. Swizzle: 16B-chunk c of row r is stored at
   chunk c ^ (r&7). Staging permutes the global SOURCE column per lane
   (global_load_lds forces LDS slot = lane order); reads XOR with lj&7. */
__global__ __launch_bounds__(256) void qkv_gemm_kernel(
    const ushort_t* __restrict__ Xb, const ushort_t* __restrict__ Wb,
    const float* __restrict__ bias,
    ushort_t* __restrict__ Qb, ushort_t* __restrict__ Kb, ushort_t* __restrict__ Vb) {
  __shared__ ushort_t As[128 * 64];
  __shared__ ushort_t Bs[128 * 64];
  const int tid = threadIdx.x;
  const int l = tid & 63, w = tid >> 6;
  const int quad = l >> 4, lj = l & 15;
  const int m0 = blockIdx.y * 128, n0 = blockIdx.x * 128;
  const int wm = (w & 1) * 64, wn = (w >> 1) * 64;

  floatx4 acc[4][4] = {};

  const int srow = w * 32 + (l >> 3);
  const int scol = ((l & 7) ^ (l >> 3)) * 8; /* swizzled source chunk */
  const ushort_t* gA = Xb + (size_t)(m0 + srow) * K_DIM + scol;
  const ushort_t* gB = Wb + (size_t)(n0 + srow) * K_DIM + scol;
  ushort_t* lA = As + (w * 32) * 64;
  ushort_t* lB = Bs + (w * 32) * 64;

  const int swr = lj & 7;

  for (int k0 = 0; k0 < K_DIM; k0 += 64) {
    __syncthreads();
#pragma unroll
    for (int c = 0; c < 4; ++c) {
      gload_lds16(gA + (size_t)(c * 8) * K_DIM + k0, lA + c * 8 * 64);
      gload_lds16(gB + (size_t)(c * 8) * K_DIM + k0, lB + c * 8 * 64);
    }
    __syncthreads();
#pragma unroll
    for (int kk = 0; kk < 2; ++kk) {
      const int ch = ((kk * 4 + quad) ^ swr) * 8;
      bf16x8 aF[4], bF[4];
#pragma unroll
      for (int i = 0; i < 4; ++i)
        aF[i] = *(const bf16x8*)(As + (wm + i * 16 + lj) * 64 + ch);
#pragma unroll
      for (int j = 0; j < 4; ++j)
        bF[j] = *(const bf16x8*)(Bs + (wn + j * 16 + lj) * 64 + ch);
#pragma unroll
      for (int i = 0; i < 4; ++i)
#pragma unroll
        for (int j = 0; j < 4; ++j)
          acc[i][j] = __builtin_amdgcn_mfma_f32_16x16x32_bf16(aF[i], bF[j], acc[i][j], 0, 0, 0);
    }
  }

  /* epilogue: n = h*192 + r; r<64 -> Q, r<128 -> K, else V */
#pragma unroll
  for (int j = 0; j < 4; ++j) {
    const int n = n0 + wn + j * 16 + lj;
    const int h = n / 192;
    const int r = n - h * 192;
    const int seg = r >> 6;
    const int d = r & 63;
    const float bv = bias[n];
    ushort_t* dst = (seg == 0) ? Qb : (seg == 1) ? Kb : Vb;
    const float scl = (seg == 0) ? QSCALE : 1.0f;
    const size_t base = (size_t)h * S_LEN * HDIM + d;
#pragma unroll
    for (int i = 0; i < 4; ++i) {
#pragma unroll
      for (int rg = 0; rg < 4; ++rg) {
        const int m = m0 + wm + i * 16 + quad * 4 + rg;
        const int bi = m >> 11;
        const int si = m & 2047;
        dst[base + ((size_t)bi * NHEADS * S_LEN + si) * HDIM] =
            f2bf((acc[i][j][rg] + bv) * scl);
      }
    }
  }
}

/* ------------------------ flash attention (v3) ------------------------
   Block: 512 threads = 8 waves, one (b,h), 128 q-rows; wave handles 16 q-rows.
   S^T = K*Q^T via mfma 16x16x32 (C: col=lane&15=q, row=quad*4+reg=key).
   P^T C-layout regs == A-operand of mfma 16x16x16bf16_1k -> free PV transform.
   NEW v3: Ks uses the XOR chunk swizzle (chunk' = chunk ^ (row&7)) applied
   at the global source during global_load_lds staging; fragment reads XOR
   with lj&7 -> 2-way max (free) instead of ~16-way conflicts. */
__global__ __launch_bounds__(512, 4) void attn_kernel(
    const ushort_t* __restrict__ Qb, const ushort_t* __restrict__ Kb,
    const ushort_t* __restrict__ Vb, float* __restrict__ out) {
  __shared__ ushort_t Ks[128 * 64];
  __shared__ ushort_t Vs[64 * 140];
  const int tid = threadIdx.x;
  const int l = tid & 63, w = tid >> 6;
  const int quad = l >> 4, lj = l & 15;
  const int bh = blockIdx.x >> 4;
  const int qt = blockIdx.x & 15;
  const int q0 = qt * 128 + w * 16;
  const size_t headoff = (size_t)bh * S_LEN * HDIM;

  /* Q fragments: B-operand, n=q=lj, k = kk*32 + quad*8 + j */
  bf16x8 qF[2];
#pragma unroll
  for (int kk = 0; kk < 2; ++kk)
    qF[kk] = *(const bf16x8*)(Qb + headoff + (size_t)(q0 + lj) * HDIM +
                              kk * 32 + quad * 8);

  floatx4 accO[4] = {};
  float m_run = -__builtin_inff();
  float l_run = 0.f;

  /* K staging with swizzled source chunk; LDS dest stays lane-contiguous */
  const int kr = tid >> 3;
  const int kc = ((tid & 7) ^ (kr & 7)) * 8;
  const ushort_t* gK = Kb + headoff + (size_t)kr * HDIM + kc;
  ushort_t* lK = Ks + tid * 8;

  /* V staging: thread covers (s pair 2sp..2sp+1) x (d quad 4dq..4dq+3), R=0,1 */
  const int dq = tid & 15;
  const int spw = tid >> 4; /* 0..31 */
  const ushort_t* gV = Vb + headoff + dq * 4;
  unsigned* Vs32 = (unsigned*)Vs;
  const int swz = (dq >> 2) << 1; /* V swizzle in u32-column units */

  const int swk = lj & 7;

  for (int kb = 0; kb < 16; ++kb) {
    const int kv0 = kb * 128;
    __syncthreads();
#pragma unroll
    for (int c = 0; c < 2; ++c)
      gload_lds16(gK + (size_t)(kv0 + c * 64) * HDIM, lK + c * 64 * 64);
#pragma unroll
    for (int R = 0; R < 2; ++R) {
      const int sp = R * 32 + spw; /* 0..63 */
      const ushort_t* g = gV + (size_t)(kv0 + 2 * sp) * HDIM;
      ushortx4 v0 = *(const ushortx4*)g;
      ushortx4 v1 = *(const ushortx4*)(g + HDIM);
      unsigned a0 = ((unsigned)(ushort_t)v0[1] << 16) | (ushort_t)v0[0];
      unsigned a1 = ((unsigned)(ushort_t)v0[3] << 16) | (ushort_t)v0[2];
      unsigned b0 = ((unsigned)(ushort_t)v1[1] << 16) | (ushort_t)v1[0];
      unsigned b1 = ((unsigned)(ushort_t)v1[3] << 16) | (ushort_t)v1[2];
      unsigned o0 = __builtin_amdgcn_perm(b0, a0, 0x05040100u);
      unsigned o1 = __builtin_amdgcn_perm(b0, a0, 0x07060302u);
      unsigned o2 = __builtin_amdgcn_perm(b1, a1, 0x05040100u);
      unsigned o3 = __builtin_amdgcn_perm(b1, a1, 0x07060302u);
      const int sp2 = sp ^ swz;
      Vs32[(4 * dq + 0) * 70 + sp2] = o0;
      Vs32[(4 * dq + 1) * 70 + sp2] = o1;
      Vs32[(4 * dq + 2) * 70 + sp2] = o2;
      Vs32[(4 * dq + 3) * 70 + sp2] = o3;
    }
    __syncthreads();

    /* S^T = K * Q^T : accST[c], key = c*16 + quad*4 + rg, q = lj */
    floatx4 accST[8];
#pragma unroll
    for (int c = 0; c < 8; ++c) {
      const ushort_t* krow = Ks + (c * 16 + lj) * 64;
      bf16x8 kF0 = *(const bf16x8*)(krow + ((quad ^ swk) * 8));
      bf16x8 kF1 = *(const bf16x8*)(krow + (((quad ^ swk) ^ 4) * 8));
      floatx4 z = {0.f, 0.f, 0.f, 0.f};
      z = __builtin_amdgcn_mfma_f32_16x16x32_bf16(kF0, qF[0], z, 0, 0, 0);
      accST[c] = __builtin_amdgcn_mfma_f32_16x16x32_bf16(kF1, qF[1], z, 0, 0, 0);
    }

    /* online softmax (scores pre-scaled by log2(e)/8 via Q) */
    float mx = accST[0][0];
#pragma unroll
    for (int c = 0; c < 8; ++c)
#pragma unroll
      for (int rg = 0; rg < 4; ++rg)
        mx = fmaxf(mx, accST[c][rg]);
    mx = fmaxf(mx, __shfl_xor(mx, 16, 64));
    mx = fmaxf(mx, __shfl_xor(mx, 32, 64));
    const float mnew = fmaxf(m_run, mx);
    const float alpha = fexp2(m_run - mnew);
    m_run = mnew;
    shortx4 aP[8];
    float lsum = 0.f;
#pragma unroll
    for (int c = 0; c < 8; ++c) {
      float p0 = fexp2(accST[c][0] - mnew);
      float p1 = fexp2(accST[c][1] - mnew);
      float p2 = fexp2(accST[c][2] - mnew);
      float p3 = fexp2(accST[c][3] - mnew);
      lsum += (p0 + p1) + (p2 + p3);
      U32x2S4 t;
      t.u[0] = pkbf(p0, p1);
      t.u[1] = pkbf(p2, p3);
      aP[c] = t.s;
    }
    l_run = l_run * alpha + lsum;

    /* rescale O: alpha per accumulator q-row (quad*4+rg) */
    {
      const int sbase = (l & 48) | (quad * 4);
      float a0 = __shfl(alpha, sbase + 0, 64);
      float a1 = __shfl(alpha, sbase + 1, 64);
      float a2 = __shfl(alpha, sbase + 2, 64);
      float a3 = __shfl(alpha, sbase + 3, 64);
#pragma unroll
      for (int dt = 0; dt < 4; ++dt) {
        accO[dt][0] *= a0;
        accO[dt][1] *= a1;
        accO[dt][2] *= a2;
        accO[dt][3] *= a3;
      }
    }

    /* O += P * V via 16x16x16 bf16; B-frag read applies V swizzle via quad^dt */
#pragma unroll
    for (int dt = 0; dt < 4; ++dt) {
      const ushort_t* vp = Vs + (dt * 16 + lj) * 140 + (quad ^ dt) * 4;
#pragma unroll
      for (int c = 0; c < 8; ++c) {
        shortx4 vF = *(const shortx4*)(vp + c * 16);
        accO[dt] = __builtin_amdgcn_mfma_f32_16x16x16bf16_1k(aP[c], vF, accO[dt], 0, 0, 0);
      }
    }
  }

  /* epilogue: O /= l, store fp32 in [b][h][s][d] flat */
  {
    float ls = l_run;
    ls += __shfl_xor(ls, 16, 64);
    ls += __shfl_xor(ls, 32, 64);
    const float inv = 1.0f / ls;
    const int sbase = (l & 48) | (quad * 4);
    float iv[4];
    iv[0] = __shfl(inv, sbase + 0, 64);
    iv[1] = __shfl(inv, sbase + 1, 64);
    iv[2] = __shfl(inv, sbase + 2, 64);
    iv[3] = __shfl(inv, sbase + 3, 64);
#pragma unroll
    for (int dt = 0; dt < 4; ++dt) {
#pragma unroll
      for (int rg = 0; rg < 4; ++rg) {
        const int q = q0 + quad * 4 + rg;
        out[headoff + (size_t)q * HDIM + dt * 16 + lj] = accO[dt][rg] * iv[rg];
      }
    }
  }
}

extern "C" void kernel_launch(void* const* d_in, const int* in_sizes, int n_in,
                              void* d_out, int out_size, void* d_ws, size_t ws_size,
                              hipStream_t stream) {
  (void)in_sizes; (void)n_in; (void)out_size; (void)ws_size;
  const float* x  = (const float*)d_in[0];
  const float* wq = (const float*)d_in[1];
  const float* bq = (const float*)d_in[2];
  float* out = (float*)d_out;

  char* ws = (char*)d_ws;
  ushort_t* Qb = (ushort_t*)(ws);
  ushort_t* Kb = (ushort_t*)(ws + 8388608);
  ushort_t* Vb = (ushort_t*)(ws + 16777216);
  ushort_t* Xb = (ushort_t*)(ws + 25165824);
  ushort_t* Wb = (ushort_t*)(ws + 33554432);

  cvt_bf16_kernel<<<7168, 256, 0, stream>>>(x, wq, Xb, Wb);
  qkv_gemm_kernel<<<dim3(N_COLS / 128, M_ROWS / 128), 256, 0, stream>>>(Xb, Wb, bq, Qb, Kb, Vb);
  attn_kernel<<<512, 512, 0, stream>>>(Qb, Kb, Vb, out);
}